// Round 4
// baseline (645.841 us; speedup 1.0000x reference)
//
#include <hip/hip_runtime.h>
#include <hip/hip_bf16.h>

#define NTOK   65536
#define KCODES 1024
#define DIM    256
#define LOSS_OFF ((size_t)NTOK * DIM)      // 16777216
#define IDX_OFF  (LOSS_OFF + 1)            // 16777217

#define MB 32          // tokens per block
#define NBLK 2048      // NTOK / MB

// ws layout (float-slot offsets)
#define WS_ESQ   0              // 1024 floats  (numpy-faithful emb_sq)
#define WS_ZSQ   1024           // 65536 floats (numpy-faithful z_sq)
#define WS_PART1 66560          // 2048 floats  (block loss partials)

// numpy pairwise_sum replica for n=256 contiguous fp32 (sum of squares).
// Structure: n=256 -> pw(a,128) + pw(a+128,128); each 128-block uses 8
// strided accumulators r[j] = sum_{i} a[8i+j] (sequential adds), combined
// as ((r0+r1)+(r2+r3))+((r4+r5)+(r6+r7)). Squares are rounded BEFORE the
// add (numpy materializes z**2 first) — asm barrier blocks FMA contraction.
__device__ __forceinline__ float np_pairwise_sq_128(const float* a) {
    float r[8];
#pragma unroll
    for (int j = 0; j < 8; ++j) {
        float v = a[j];
        float sq = v * v;
        asm volatile("" : "+v"(sq));
        r[j] = sq;
    }
    for (int i = 8; i < 128; i += 8) {
#pragma unroll
        for (int j = 0; j < 8; ++j) {
            float v = a[i + j];
            float sq = v * v;
            asm volatile("" : "+v"(sq));
            r[j] += sq;
        }
    }
    return ((r[0] + r[1]) + (r[2] + r[3])) + ((r[4] + r[5]) + (r[6] + r[7]));
}

__device__ __forceinline__ float np_rowsq256(const float* row) {
    float slo = np_pairwise_sq_128(row);
    float shi = np_pairwise_sq_128(row + 128);
    return slo + shi;
}

// ---------------- kernel 1: numpy-faithful row sum-of-squares ----------------
__global__ __launch_bounds__(256) void vq_rowsq(const float* __restrict__ rows,
                                                float* __restrict__ out, int nrows) {
    int t = blockIdx.x * 256 + threadIdx.x;
    if (t >= nrows) return;
    out[t] = np_rowsq256(rows + (size_t)t * DIM);
}

// ---------------- kernel 2: faithful fp32 distances + argmin + outputs ----------------
__global__ __launch_bounds__(256, 2) void vq_main(const float* __restrict__ z,
                                                  const float* __restrict__ emb,
                                                  const float* __restrict__ ws_zsq,
                                                  const float* __restrict__ ws_esq,
                                                  float* __restrict__ ws_part,
                                                  float* __restrict__ dout) {
    __shared__ __align__(16) float zs[MB * DIM];     // 32 KB
    __shared__ __align__(16) float es[32 * 257];     // 32.9 KB transposed e-chunk
    __shared__ float esq[KCODES];                    // 4 KB
    __shared__ float wloss[4];

    const int tid = threadIdx.x;
    const int bid = blockIdx.x;
    const int t0 = bid * MB;

#pragma unroll
    for (int q = 0; q < 8; ++q) {
        int idx = q * 1024 + tid * 4;
        *(float4*)&zs[idx] = *(const float4*)&z[(size_t)t0 * DIM + idx];
    }
    for (int i = tid; i < KCODES; i += 256) esq[i] = ws_esq[i];

    const int r = tid >> 6;    // wave id: tokens r*8..r*8+7
    const int c = tid & 63;    // lane: codes {n*256 + j*64 + c}
    const int u = tid & 7;     // staging k-quad
    const int rr = tid >> 3;   // staging code row

    // per-token numpy-faithful z_sq (broadcast loads, L2-hot)
    float zsqv[8];
#pragma unroll
    for (int i = 0; i < 8; i++) zsqv[i] = ws_zsq[t0 + r * 8 + i];

    float d1[8];
    int   i1[8];
#pragma unroll
    for (int i = 0; i < 8; i++) { d1[i] = 3.4e38f; i1[i] = 0; }

    for (int n = 0; n < 4; ++n) {            // code tiles of 256
        float acc[8][4];
#pragma unroll
        for (int i = 0; i < 8; i++)
#pragma unroll
            for (int j = 0; j < 4; j++) acc[i][j] = 0.f;

        for (int kc = 0; kc < 8; ++kc) {     // k chunks of 32, ascending
            __syncthreads();
#pragma unroll
            for (int q = 0; q < 8; ++q) {
                int cl = q * 32 + rr;
                float4 v = *(const float4*)&emb[(size_t)(n * 256 + cl) * DIM + kc * 32 + u * 4];
                es[(u * 4 + 0) * 257 + cl] = v.x;
                es[(u * 4 + 1) * 257 + cl] = v.y;
                es[(u * 4 + 2) * 257 + cl] = v.z;
                es[(u * 4 + 3) * 257 + cl] = v.w;
            }
            __syncthreads();
            // strictly ascending k, single accumulator -> bitwise sequential FMA chain
#pragma unroll
            for (int kk = 0; kk < 32; kk += 4) {
                float4 av[8];
#pragma unroll
                for (int i = 0; i < 8; i++)
                    av[i] = *(const float4*)&zs[(r * 8 + i) * DIM + kc * 32 + kk];
                float bs[4][4];
#pragma unroll
                for (int s = 0; s < 4; s++)
#pragma unroll
                    for (int j = 0; j < 4; j++)
                        bs[s][j] = es[(kk + s) * 257 + j * 64 + c];
#pragma unroll
                for (int s = 0; s < 4; s++) {
#pragma unroll
                    for (int i = 0; i < 8; i++) {
                        float a_is = ((const float*)&av[i])[s];
#pragma unroll
                        for (int j = 0; j < 4; j++)
                            acc[i][j] = fmaf(a_is, bs[s][j], acc[i][j]);
                    }
                }
            }
        }
        // faithful fp32 distance: d = fl( fl(zsq + esq_k) - 2*dot ), 2*dot exact
#pragma unroll
        for (int j = 0; j < 4; j++) {
            int code = n * 256 + j * 64 + c;
            float eq = esq[code];
#pragma unroll
            for (int i = 0; i < 8; i++) {
                float t1 = zsqv[i] + eq;
                float d  = t1 - 2.0f * acc[i][j];
                if (d < d1[i]) { d1[i] = d; i1[i] = code; }   // ascending code -> first-index ties
            }
        }
    }

    // cross-lane argmin merge, first-index tie-break (ties are COMMON here)
#pragma unroll
    for (int i = 0; i < 8; i++) {
#pragma unroll
        for (int m = 1; m < 64; m <<= 1) {
            float od = __shfl_xor(d1[i], m, 64);
            int   oi = __shfl_xor(i1[i], m, 64);
            if (od < d1[i] || (od == d1[i] && oi < i1[i])) { d1[i] = od; i1[i] = oi; }
        }
    }

    // epilogue: gather z_q, write outputs, loss partial
    float lsum = 0.f;
#pragma unroll
    for (int i = 0; i < 8; i++) {
        int tl = r * 8 + i;
        int idx = i1[i];
        float4 ev = *(const float4*)&emb[(size_t)idx * DIM + c * 4];
        float4 zv = *(const float4*)&zs[tl * DIM + c * 4];
        *(float4*)&dout[(size_t)(t0 + tl) * DIM + c * 4] = ev;
        float dx = zv.x - ev.x, dy = zv.y - ev.y;
        float dz = zv.z - ev.z, dw = zv.w - ev.w;
        lsum += dx * dx + dy * dy + dz * dz + dw * dw;
        if (c == 0) dout[IDX_OFF + t0 + tl] = (float)idx;
    }
#pragma unroll
    for (int m = 1; m < 64; m <<= 1) lsum += __shfl_xor(lsum, m, 64);
    if (c == 0) wloss[r] = lsum;
    __syncthreads();
    if (tid == 0) ws_part[bid] = wloss[0] + wloss[1] + wloss[2] + wloss[3];
}

// ---------------- kernel 3: deterministic loss finalize ----------------
__global__ __launch_bounds__(256) void vq_final(const float* __restrict__ part1,
                                                float* __restrict__ dout) {
    __shared__ double dred[4];
    double s = 0.0;
    for (int i = threadIdx.x; i < NBLK; i += 256) s += (double)part1[i];
#pragma unroll
    for (int m = 1; m < 64; m <<= 1) s += __shfl_xor(s, m, 64);
    if ((threadIdx.x & 63) == 0) dred[threadIdx.x >> 6] = s;
    __syncthreads();
    if (threadIdx.x == 0) {
        double tot = dred[0] + dred[1] + dred[2] + dred[3];
        dout[LOSS_OFF] = (float)(tot * 1.25 / 16777216.0);
    }
}

extern "C" void kernel_launch(void* const* d_in, const int* in_sizes, int n_in,
                              void* d_out, int out_size, void* d_ws, size_t ws_size,
                              hipStream_t stream) {
    const float* z   = (const float*)d_in[0];
    const float* emb = (const float*)d_in[1];
    float* out = (float*)d_out;
    float* f   = (float*)d_ws;

    float* esq   = f + WS_ESQ;
    float* zsq   = f + WS_ZSQ;
    float* part1 = f + WS_PART1;

    vq_rowsq<<<(KCODES + 255) / 256, 256, 0, stream>>>(emb, esq, KCODES);
    vq_rowsq<<<(NTOK   + 255) / 256, 256, 0, stream>>>(z,   zsq, NTOK);
    vq_main <<<NBLK, 256, 0, stream>>>(z, emb, zsq, esq, part1, out);
    vq_final<<<1,    256, 0, stream>>>(part1, out);
}